// Round 1
// baseline (274.894 us; speedup 1.0000x reference)
//
#include <hip/hip_runtime.h>

#define PI_F 3.14159f

// ---------------------------------------------------------------------------
// Kernel A: per-batch MLP head -> per-channel affine params.
// 8 batches per block; 256 threads.
// params layout: [B][20][8] = (m00, m01, m10, m11, tx, ty, pad, pad)
// ---------------------------------------------------------------------------
__global__ __launch_bounds__(256) void params_kernel(
    const float* __restrict__ pc, const float* __restrict__ W1, const float* __restrict__ b1,
    const float* __restrict__ Ws, const float* __restrict__ bs,
    const float* __restrict__ Wr, const float* __restrict__ br,
    const float* __restrict__ Wt, const float* __restrict__ bt,
    float* __restrict__ params)
{
    __shared__ float para[8][256];
    __shared__ float hbuf[8][260];   // padded: avoids same-bank for different g
    __shared__ float raw[8][80];

    const int t  = threadIdx.x;
    const int b0 = blockIdx.x * 8;

    #pragma unroll
    for (int g = 0; g < 8; ++g) para[g][t] = pc[(size_t)(b0 + g) * 256 + t];
    __syncthreads();

    // h = relu(para @ W1 + b1): thread t owns column t for all 8 batches.
    float acc[8];
    #pragma unroll
    for (int g = 0; g < 8; ++g) acc[g] = b1[t];
    for (int k = 0; k < 256; ++k) {
        float w = W1[k * 256 + t];   // coalesced row of W1
        #pragma unroll
        for (int g = 0; g < 8; ++g) acc[g] = fmaf(para[g][k], w, acc[g]);
    }
    #pragma unroll
    for (int g = 0; g < 8; ++g) hbuf[g][t] = fmaxf(acc[g], 0.0f);
    __syncthreads();

    // 8 batches x 80 output columns (20 scale, 20 rot, 40 trans)
    for (int task = t; task < 640; task += 256) {
        int g   = task / 80;
        int col = task - g * 80;
        const float* Wcol;
        float bias;
        int stride;
        if (col < 20)      { Wcol = Ws + col;        bias = bs[col];      stride = 20; }
        else if (col < 40) { Wcol = Wr + (col - 20); bias = br[col - 20]; stride = 20; }
        else               { Wcol = Wt + (col - 40); bias = bt[col - 40]; stride = 40; }
        float a = bias;
        for (int k = 0; k < 256; ++k) a = fmaf(hbuf[g][k], Wcol[k * stride], a);
        raw[g][col] = a;
    }
    __syncthreads();

    // fold activations into the 2x2 affine + translation
    for (int task = t; task < 160; task += 256) {
        int g = task / 20;
        int f = task - g * 20;
        float sc  = 2.0f / (1.0f + expf(-raw[g][f]));
        float ang = PI_F * tanhf(raw[g][20 + f]);
        float tx  = tanhf(raw[g][40 + 2 * f]);
        float ty  = tanhf(raw[g][40 + 2 * f + 1]);
        float c = cosf(ang), s = sinf(ang);
        float* o = params + ((size_t)(b0 + g) * 20 + f) * 8;
        o[0] = sc * c;  o[1] = -sc * s;
        o[2] = sc * s;  o[3] = sc * c;
        o[4] = tx;      o[5] = ty;
        o[6] = 0.0f;    o[7] = 0.0f;
    }
}

// ---------------------------------------------------------------------------
// Kernel B: one block per batch. Whole (20,18,18) volume staged in LDS;
// trilinear zero-padded sampling of the warped grid; coalesced stores.
// ---------------------------------------------------------------------------
__global__ __launch_bounds__(256) void sample_kernel(
    const float* __restrict__ fmap, const float* __restrict__ params,
    float* __restrict__ out)
{
    __shared__ __align__(16) float vol[6480];   // 20*18*18
    __shared__ float prm[160];                  // 20 channels * 8

    const int b = blockIdx.x;
    const int t = threadIdx.x;

    const float4* src4 = (const float4*)(fmap + (size_t)b * 6480);
    float4* vol4 = (float4*)vol;
    for (int i = t; i < 1620; i += 256) vol4[i] = src4[i];
    if (t < 160) prm[t] = params[(size_t)b * 160 + t];
    __syncthreads();

    float* outb = out + (size_t)b * 6480;

    for (int p = t; p < 6480; p += 256) {
        int d   = p / 324;            // channel / depth slice
        int rem = p - d * 324;
        int hy  = rem / 18;
        int wxi = rem - hy * 18;

        float X = wxi * (2.0f / 17.0f) - 1.0f;
        float Y = hy  * (2.0f / 17.0f) - 1.0f;

        const float* pr = prm + d * 8;
        float gx = fmaf(pr[0], X, fmaf(pr[1], Y, pr[4]));
        float gy = fmaf(pr[2], X, fmaf(pr[3], Y, pr[5]));

        // ((g+1)*18 - 1)*0.5 = g*9 + 8.5 ; iz = 20d/19 - 0.5 (z not warped)
        float ix = fmaf(gx, 9.0f, 8.5f);
        float iy = fmaf(gy, 9.0f, 8.5f);
        float iz = fmaf((float)d, 20.0f / 19.0f, -0.5f);

        float fx = floorf(ix), fy = floorf(iy), fz = floorf(iz);
        float u1 = ix - fx, v1 = iy - fy, w1 = iz - fz;
        float u0 = 1.0f - u1, v0 = 1.0f - v1, w0 = 1.0f - w1;

        int x0 = (int)fx, y0 = (int)fy, z0 = (int)fz;
        int x1 = x0 + 1,  y1 = y0 + 1,  z1 = z0 + 1;

        // per-axis zero-padding masks (product == all-axes-valid test)
        float ax0 = ((unsigned)x0 < 18u) ? u0 : 0.0f;
        float ax1 = ((unsigned)x1 < 18u) ? u1 : 0.0f;
        float ay0 = ((unsigned)y0 < 18u) ? v0 : 0.0f;
        float ay1 = ((unsigned)y1 < 18u) ? v1 : 0.0f;
        float az0 = ((unsigned)z0 < 20u) ? w0 : 0.0f;
        float az1 = ((unsigned)z1 < 20u) ? w1 : 0.0f;

        int xc0 = min(max(x0, 0), 17), xc1 = min(max(x1, 0), 17);
        int yc0 = min(max(y0, 0), 17), yc1 = min(max(y1, 0), 17);
        int zc0 = min(max(z0, 0), 19), zc1 = min(max(z1, 0), 19);

        int zb0 = zc0 * 324, zb1 = zc1 * 324;
        int yb0 = yc0 * 18,  yb1 = yc1 * 18;

        float v000 = vol[zb0 + yb0 + xc0], v001 = vol[zb0 + yb0 + xc1];
        float v010 = vol[zb0 + yb1 + xc0], v011 = vol[zb0 + yb1 + xc1];
        float v100 = vol[zb1 + yb0 + xc0], v101 = vol[zb1 + yb0 + xc1];
        float v110 = vol[zb1 + yb1 + xc0], v111 = vol[zb1 + yb1 + xc1];

        float r0 = fmaf(fmaf(v001, ax1, v000 * ax0), ay0,
                        fmaf(v011, ax1, v010 * ax0) * ay1);
        float r1 = fmaf(fmaf(v101, ax1, v100 * ax0), ay0,
                        fmaf(v111, ax1, v110 * ax0) * ay1);

        outb[p] = fmaf(r0, az0, r1 * az1);
    }
}

extern "C" void kernel_launch(void* const* d_in, const int* in_sizes, int n_in,
                              void* d_out, int out_size, void* d_ws, size_t ws_size,
                              hipStream_t stream)
{
    const float* fmap = (const float*)d_in[0];
    const float* pc   = (const float*)d_in[1];
    const float* W1   = (const float*)d_in[2];
    const float* b1   = (const float*)d_in[3];
    const float* Ws   = (const float*)d_in[4];
    const float* bs   = (const float*)d_in[5];
    const float* Wr   = (const float*)d_in[6];
    const float* br   = (const float*)d_in[7];
    const float* Wt   = (const float*)d_in[8];
    const float* bt   = (const float*)d_in[9];
    float* out    = (float*)d_out;
    float* params = (float*)d_ws;     // B*20*8 floats = 2.6 MB

    const int B = in_sizes[0] / (20 * 18 * 18);   // 4096

    params_kernel<<<B / 8, 256, 0, stream>>>(pc, W1, b1, Ws, bs, Wr, br, Wt, bt, params);
    sample_kernel<<<B, 256, 0, stream>>>(fmap, params, out);
}

// Round 2
// 262.014 us; speedup vs baseline: 1.0492x; 1.0492x over previous
//
#include <hip/hip_runtime.h>

#define PI_F 3.14159f

// ---------------------------------------------------------------------------
// Kernel A: per-batch MLP head -> per-channel PRE-SCALED affine params.
// params layout: [B][20][8] = (P0..P5, 0, 0) with
//   ix = P0*X + P1*Y + P2 ;  iy = P3*X + P4*Y + P5
// where the *9+8.5 grid_sample scaling AND the +1 LDS-pad shift are folded in.
// ---------------------------------------------------------------------------
__global__ __launch_bounds__(256) void params_kernel(
    const float* __restrict__ pc, const float* __restrict__ W1, const float* __restrict__ b1,
    const float* __restrict__ Ws, const float* __restrict__ bs,
    const float* __restrict__ Wr, const float* __restrict__ br,
    const float* __restrict__ Wt, const float* __restrict__ bt,
    float* __restrict__ params)
{
    __shared__ float para[8][256];
    __shared__ float hbuf[8][260];
    __shared__ float raw[8][80];

    const int t  = threadIdx.x;
    const int b0 = blockIdx.x * 8;

    #pragma unroll
    for (int g = 0; g < 8; ++g) para[g][t] = pc[(size_t)(b0 + g) * 256 + t];
    __syncthreads();

    float acc[8];
    #pragma unroll
    for (int g = 0; g < 8; ++g) acc[g] = b1[t];
    for (int k = 0; k < 256; ++k) {
        float w = W1[k * 256 + t];
        #pragma unroll
        for (int g = 0; g < 8; ++g) acc[g] = fmaf(para[g][k], w, acc[g]);
    }
    #pragma unroll
    for (int g = 0; g < 8; ++g) hbuf[g][t] = fmaxf(acc[g], 0.0f);
    __syncthreads();

    for (int task = t; task < 640; task += 256) {
        int g   = task / 80;
        int col = task - g * 80;
        const float* Wcol;
        float bias;
        int stride;
        if (col < 20)      { Wcol = Ws + col;        bias = bs[col];      stride = 20; }
        else if (col < 40) { Wcol = Wr + (col - 20); bias = br[col - 20]; stride = 20; }
        else               { Wcol = Wt + (col - 40); bias = bt[col - 40]; stride = 40; }
        float a = bias;
        for (int k = 0; k < 256; ++k) a = fmaf(hbuf[g][k], Wcol[k * stride], a);
        raw[g][col] = a;
    }
    __syncthreads();

    for (int task = t; task < 160; task += 256) {
        int g = task / 20;
        int f = task - g * 20;
        float sc  = 2.0f / (1.0f + expf(-raw[g][f]));
        float ang = PI_F * tanhf(raw[g][20 + f]);
        float tx  = tanhf(raw[g][40 + 2 * f]);
        float ty  = tanhf(raw[g][40 + 2 * f + 1]);
        float c = cosf(ang), s = sinf(ang);
        float* o = params + ((size_t)(b0 + g) * 20 + f) * 8;
        o[0] = 9.0f * sc * c;  o[1] = -9.0f * sc * s;  o[2] = fmaf(9.0f, tx, 9.5f);
        o[3] = 9.0f * sc * s;  o[4] =  9.0f * sc * c;  o[5] = fmaf(9.0f, ty, 9.5f);
        o[6] = 0.0f;           o[7] = 0.0f;
    }
}

// ---------------------------------------------------------------------------
// Kernel B: one block (384 threads) per batch. Volume staged in LDS with a
// 1-cell zero pad on x/y ([z:20][y:20][x:20] = 32000 B -> 5 blocks/CU).
// Threads t<324 each own one (y,x); channel loop fully unrolled at compile
// time so all z-tap indices/weights/validity are constants.
// ---------------------------------------------------------------------------
template<int D>
__device__ __forceinline__ void slice(const float* __restrict__ pb,
                                      const float* vol,
                                      float X, float Y,
                                      float* __restrict__ ob)
{
    constexpr int   Z0  = (D == 0) ? -1 : (40 * D - 19) / 38;
    constexpr float W1v = ((40.0f * D - 19.0f) - 38.0f * (float)Z0) / 38.0f;
    constexpr float W0v = 1.0f - W1v;
    constexpr bool  V0  = (Z0 >= 0);
    constexpr bool  V1  = (Z0 + 1 <= 19);

    float4 pA = *(const float4*)(pb + D * 8);
    float2 pB = *(const float2*)(pb + D * 8 + 4);

    float ix = fmaf(pA.x, X, fmaf(pA.y, Y, pA.z));   // already +1-shifted
    float iy = fmaf(pA.w, X, fmaf(pB.x, Y, pB.y));

    float fx = floorf(ix), fy = floorf(iy);
    float u1 = ix - fx, v1 = iy - fy;
    float u0 = 1.0f - u1, v0 = 1.0f - v1;

    int x0 = (int)fx, y0 = (int)fy;                  // padded coords
    int xc0 = min(max(x0, 0), 19), xc1 = min(max(x0 + 1, 0), 19);
    int yc0 = min(max(y0, 0), 19), yc1 = min(max(y0 + 1, 0), 19);

    int a00 = yc0 * 20 + xc0, a01 = yc0 * 20 + xc1;
    int a10 = yc1 * 20 + xc0, a11 = yc1 * 20 + xc1;

    float r0 = 0.0f, r1 = 0.0f;
    if constexpr (V0) {
        const float* s = vol + Z0 * 400;
        float t00 = s[a00], t01 = s[a01], t10 = s[a10], t11 = s[a11];
        r0 = fmaf(fmaf(t01, u1, t00 * u0), v0, fmaf(t11, u1, t10 * u0) * v1);
    }
    if constexpr (V1) {
        const float* s = vol + (Z0 + 1) * 400;
        float t00 = s[a00], t01 = s[a01], t10 = s[a10], t11 = s[a11];
        r1 = fmaf(fmaf(t01, u1, t00 * u0), v0, fmaf(t11, u1, t10 * u0) * v1);
    }

    float r;
    if constexpr (!V0)      r = r1 * W1v;
    else if constexpr (!V1) r = r0 * W0v;
    else                    r = fmaf(r0, W0v, r1 * W1v);

    ob[D * 324] = r;
}

template<int D>
struct Run {
    static __device__ __forceinline__ void go(const float* __restrict__ pb,
                                              const float* vol,
                                              float X, float Y,
                                              float* __restrict__ ob) {
        slice<D>(pb, vol, X, Y, ob);
        Run<D + 1>::go(pb, vol, X, Y, ob);
    }
};
template<>
struct Run<20> {
    static __device__ __forceinline__ void go(const float*, const float*,
                                              float, float, float*) {}
};

__global__ __launch_bounds__(384) void sample_kernel(
    const float* __restrict__ fmap, const float* __restrict__ params,
    float* __restrict__ out)
{
    __shared__ __align__(16) float vol[8000];   // [z:20][y:20][x:20], x/y pads = 0

    const int b = blockIdx.x;
    const int t = threadIdx.x;

    float4* v4 = (float4*)vol;
    for (int i = t; i < 2000; i += 384) v4[i] = make_float4(0.f, 0.f, 0.f, 0.f);
    __syncthreads();

    const float* fb = fmap + (size_t)b * 6480;
    int yy = 0, xx = 0;
    if (t < 324) {
        yy = t / 18;
        xx = t - yy * 18;
        const int w = (yy + 1) * 20 + (xx + 1);
        #pragma unroll
        for (int dz = 0; dz < 20; ++dz)
            vol[dz * 400 + w] = fb[dz * 324 + t];
    }
    __syncthreads();

    if (t >= 324) return;   // no further barriers

    const float X = xx * (2.0f / 17.0f) - 1.0f;
    const float Y = yy * (2.0f / 17.0f) - 1.0f;
    const float* pb = params + (size_t)b * 160;
    float* ob = out + (size_t)b * 6480 + t;

    Run<0>::go(pb, vol, X, Y, ob);
}

extern "C" void kernel_launch(void* const* d_in, const int* in_sizes, int n_in,
                              void* d_out, int out_size, void* d_ws, size_t ws_size,
                              hipStream_t stream)
{
    const float* fmap = (const float*)d_in[0];
    const float* pc   = (const float*)d_in[1];
    const float* W1   = (const float*)d_in[2];
    const float* b1   = (const float*)d_in[3];
    const float* Ws   = (const float*)d_in[4];
    const float* bs   = (const float*)d_in[5];
    const float* Wr   = (const float*)d_in[6];
    const float* br   = (const float*)d_in[7];
    const float* Wt   = (const float*)d_in[8];
    const float* bt   = (const float*)d_in[9];
    float* out    = (float*)d_out;
    float* params = (float*)d_ws;     // B*20*8 floats

    const int B = in_sizes[0] / (20 * 18 * 18);   // 4096

    params_kernel<<<B / 8, 256, 0, stream>>>(pc, W1, b1, Ws, bs, Wr, br, Wt, bt, params);
    sample_kernel<<<B, 384, 0, stream>>>(fmap, params, out);
}

// Round 3
// 243.422 us; speedup vs baseline: 1.1293x; 1.0764x over previous
//
#include <hip/hip_runtime.h>

#define PI_F 3.14159f

// ---------------------------------------------------------------------------
// Kernel A: per-batch MLP head -> per-channel PRE-SCALED affine params.
// 4 batches per block, 256 threads. Phase 1 keeps para in registers and
// broadcasts with v_readlane (no LDS). params layout: [B][20][8] =
// (P0..P5, 0, 0):  ix = P0*X + P1*Y + P2 ; iy = P3*X + P4*Y + P5
// with grid_sample *9+8.5 scaling and the +2 LDS-pad shift folded in.
// ---------------------------------------------------------------------------
__global__ __launch_bounds__(256) void params_kernel(
    const float* __restrict__ pc, const float* __restrict__ W1, const float* __restrict__ b1,
    const float* __restrict__ Ws, const float* __restrict__ bs,
    const float* __restrict__ Wr, const float* __restrict__ br,
    const float* __restrict__ Wt, const float* __restrict__ bt,
    float* __restrict__ params)
{
    __shared__ float hbuf[4][260];   // 260-stride: float4-aligned rows (1040 B)
    __shared__ float raw[4][80];

    const int t    = threadIdx.x;
    const int lane = t & 63;
    const int b0   = blockIdx.x * 4;

    // para held in registers: lane l of each wave holds para[g][c*64+l]
    float pval[4][4];
    #pragma unroll
    for (int g = 0; g < 4; ++g)
        #pragma unroll
        for (int c = 0; c < 4; ++c)
            pval[g][c] = pc[(size_t)(b0 + g) * 256 + c * 64 + lane];

    float acc[4];
    #pragma unroll
    for (int g = 0; g < 4; ++g) acc[g] = b1[t];

    #pragma unroll
    for (int c = 0; c < 4; ++c) {
        for (int kk = 0; kk < 64; ++kk) {
            float w = W1[(c * 64 + kk) * 256 + t];   // coalesced row of W1
            #pragma unroll
            for (int g = 0; g < 4; ++g) {
                float pk = __int_as_float(
                    __builtin_amdgcn_readlane(__float_as_int(pval[g][c]), kk));
                acc[g] = fmaf(pk, w, acc[g]);
            }
        }
    }
    #pragma unroll
    for (int g = 0; g < 4; ++g) hbuf[g][t] = fmaxf(acc[g], 0.0f);
    __syncthreads();

    // 4 batches x 80 columns (20 scale, 20 rot, 40 trans)
    for (int task = t; task < 320; task += 256) {
        int g   = task / 80;
        int col = task - g * 80;
        const float* Wcol;
        float bias;
        int stride;
        if (col < 20)      { Wcol = Ws + col;        bias = bs[col];      stride = 20; }
        else if (col < 40) { Wcol = Wr + (col - 20); bias = br[col - 20]; stride = 20; }
        else               { Wcol = Wt + (col - 40); bias = bt[col - 40]; stride = 40; }
        const float4* h4 = (const float4*)hbuf[g];
        float a = bias;
        for (int k4 = 0; k4 < 64; ++k4) {
            float4 h = h4[k4];
            int k = k4 * 4;
            a = fmaf(h.x, Wcol[k * stride], a);
            a = fmaf(h.y, Wcol[(k + 1) * stride], a);
            a = fmaf(h.z, Wcol[(k + 2) * stride], a);
            a = fmaf(h.w, Wcol[(k + 3) * stride], a);
        }
        raw[g][col] = a;
    }
    __syncthreads();

    for (int task = t; task < 80; task += 256) {
        int g = task / 20;
        int f = task - g * 20;
        float sc  = 2.0f / (1.0f + expf(-raw[g][f]));
        float ang = PI_F * tanhf(raw[g][20 + f]);
        float tx  = tanhf(raw[g][40 + 2 * f]);
        float ty  = tanhf(raw[g][40 + 2 * f + 1]);
        float c = cosf(ang), s = sinf(ang);
        float* o = params + ((size_t)(b0 + g) * 20 + f) * 8;
        o[0] = 9.0f * sc * c;  o[1] = -9.0f * sc * s;  o[2] = fmaf(9.0f, tx, 10.5f);
        o[3] = 9.0f * sc * s;  o[4] =  9.0f * sc * c;  o[5] = fmaf(9.0f, ty, 10.5f);
        o[6] = 0.0f;           o[7] = 0.0f;
    }
}

// ---------------------------------------------------------------------------
// Kernel B: one block (384 threads) per batch.
// Staging pre-blends the fixed z-interpolation: channel image
//   I_D = W0(D)*slice(Z0) + W1(D)*slice(Z0+1)
// stored in LDS as [20][22][22] with a 2-cell zero pad on x/y. Sampling is
// then pure 2D bilinear: clamp the tap-pair BASE to [0,20] so the 4 taps are
// s[0],s[1],s[22],s[23] -> two ds_read2_b32 per point per channel.
// ---------------------------------------------------------------------------
template<int D>
struct Stage {
    static constexpr int   Z0  = (D == 0) ? -1 : (40 * D - 19) / 38;
    static constexpr float W1v = (float)((40.0 * D - 19.0) / 38.0 - (double)Z0);
    static constexpr float W0v = 1.0f - W1v;
    static constexpr bool  V0  = (Z0 >= 0);
    static constexpr bool  V1  = (Z0 + 1 <= 19);

    static __device__ __forceinline__ void go(const float (&v)[20], float* vol, int w) {
        float I;
        if constexpr (V0 && V1)  I = fmaf(v[Z0], W0v, v[Z0 + 1] * W1v);
        else if constexpr (V0)   I = v[Z0] * W0v;
        else                     I = v[(Z0 + 1) < 0 ? 0 : (Z0 + 1)] * W1v;
        vol[D * 484 + w] = I;
        Stage<D + 1>::go(v, vol, w);
    }
};
template<> struct Stage<20> {
    static __device__ __forceinline__ void go(const float (&)[20], float*, int) {}
};

template<int D>
struct Run {
    static __device__ __forceinline__ void go(const float* __restrict__ pb,
                                              const float* vol,
                                              float X, float Y,
                                              float* __restrict__ ob) {
        float4 pA = *(const float4*)(pb + D * 8);
        float2 pB = *(const float2*)(pb + D * 8 + 4);

        float ix = fmaf(pA.x, X, fmaf(pA.y, Y, pA.z));   // padded coords
        float iy = fmaf(pA.w, X, fmaf(pB.x, Y, pB.y));

        float fx = floorf(ix), fy = floorf(iy);
        float u1 = ix - fx, v1 = iy - fy;
        float u0 = 1.0f - u1, v0 = 1.0f - v1;

        int xb = min(max((int)fx, 0), 20);
        int yb = min(max((int)fy, 0), 20);

        const float* s = vol + D * 484 + yb * 22 + xb;
        float t00 = s[0], t01 = s[1], t10 = s[22], t11 = s[23];

        float r = fmaf(fmaf(t01, u1, t00 * u0), v0,
                       fmaf(t11, u1, t10 * u0) * v1);
        ob[D * 324] = r;

        Run<D + 1>::go(pb, vol, X, Y, ob);
    }
};
template<> struct Run<20> {
    static __device__ __forceinline__ void go(const float*, const float*,
                                              float, float, float*) {}
};

__global__ __launch_bounds__(384) void sample_kernel(
    const float* __restrict__ fmap, const float* __restrict__ params,
    float* __restrict__ out)
{
    __shared__ __align__(16) float vol[20 * 484];   // [z:20][y:22][x:22]

    const int b = blockIdx.x;
    const int t = threadIdx.x;

    float4* v4 = (float4*)vol;
    for (int i = t; i < 2420; i += 384) v4[i] = make_float4(0.f, 0.f, 0.f, 0.f);
    __syncthreads();

    int yy = 0, xx = 0;
    if (t < 324) {
        yy = t / 18;
        xx = t - yy * 18;
        const float* fb = fmap + (size_t)b * 6480;
        float v[20];
        #pragma unroll
        for (int dz = 0; dz < 20; ++dz) v[dz] = fb[dz * 324 + t];
        const int w = (yy + 2) * 22 + (xx + 2);
        Stage<0>::go(v, vol, w);
    }
    __syncthreads();

    if (t >= 324) return;

    const float X = xx * (2.0f / 17.0f) - 1.0f;
    const float Y = yy * (2.0f / 17.0f) - 1.0f;
    const float* pb = params + (size_t)b * 160;
    float* ob = out + (size_t)b * 6480 + t;

    Run<0>::go(pb, vol, X, Y, ob);
}

extern "C" void kernel_launch(void* const* d_in, const int* in_sizes, int n_in,
                              void* d_out, int out_size, void* d_ws, size_t ws_size,
                              hipStream_t stream)
{
    const float* fmap = (const float*)d_in[0];
    const float* pc   = (const float*)d_in[1];
    const float* W1   = (const float*)d_in[2];
    const float* b1   = (const float*)d_in[3];
    const float* Ws   = (const float*)d_in[4];
    const float* bs   = (const float*)d_in[5];
    const float* Wr   = (const float*)d_in[6];
    const float* br   = (const float*)d_in[7];
    const float* Wt   = (const float*)d_in[8];
    const float* bt   = (const float*)d_in[9];
    float* out    = (float*)d_out;
    float* params = (float*)d_ws;     // B*20*8 floats

    const int B = in_sizes[0] / (20 * 18 * 18);   // 4096

    params_kernel<<<B / 4, 256, 0, stream>>>(pc, W1, b1, Ws, bs, Wr, br, Wt, bt, params);
    sample_kernel<<<B, 384, 0, stream>>>(fmap, params, out);
}